// Round 1
// baseline (154.927 us; speedup 1.0000x reference)
//
#include <hip/hip_runtime.h>

#define BB 4
#define CC 3
#define HH 512
#define WW 512
#define RR 5
#define KS 11
#define EPS_F 1e-5f
// -log2(e), folded into the prepass so the per-tap weight is exp2(d2 * a)
#define NLOG2E 1.44269504088896340736f

// Prepass: a[b,y,x] = -log2(e) / (2*psf^2 + eps).
// Per-tap weight then = exp2(d2 * a) == exp(-d2/(2 w^2 + eps)).
__global__ __launch_bounds__(256) void psf_prep_kernel(const float* __restrict__ psf,
                                                       float* __restrict__ A, int n) {
    int i = blockIdx.x * 256 + threadIdx.x;
    if (i < n) {
        float w = psf[i];
        A[i] = -NLOG2E / (2.0f * w * w + EPS_F);
    }
}

template <bool INTERIOR>
__device__ __forceinline__ void pixel_body(const float* __restrict__ img,   // b-th image plane set (C,H,W)
                                           const float* __restrict__ Ab,    // b-th a plane (H,W)
                                           float* __restrict__ outb,        // b-th out plane set (C,H,W)
                                           int x, int y) {
    float wsum = 0.0f, o0 = 0.0f, o1 = 0.0f, o2 = 0.0f;
#pragma unroll
    for (int dy = 0; dy < KS; ++dy) {
        int ny = y + dy - RR;
        int nyc;
        if (INTERIOR) {
            nyc = ny;
        } else {
            nyc = ny < 0 ? 0 : (ny > HH - 1 ? HH - 1 : ny);
        }
#pragma unroll
        for (int dx = 0; dx < KS; ++dx) {
            int nx = x + dx - RR;
            int nxc;
            bool in = true;
            if (INTERIOR) {
                nxc = nx;
            } else {
                nxc = nx < 0 ? 0 : (nx > WW - 1 ? WW - 1 : nx);
                in = ((unsigned)ny < (unsigned)HH) && ((unsigned)nx < (unsigned)WW);
            }
            const float d2 = (float)((dy - RR) * (dy - RR) + (dx - RR) * (dx - RR));
            int ni = nyc * WW + nxc;
            float a  = Ab[ni];
            float k  = exp2f(d2 * a);
            if (!INTERIOR) k = in ? k : 0.0f;   // zero weight outside image (mask mv)
            float i0 = img[ni];
            float i1 = img[HH * WW + ni];
            float i2 = img[2 * HH * WW + ni];
            wsum += k;
            o0 += i0 * k;
            o1 += i1 * k;
            o2 += i2 * k;
        }
    }
    // wsum >= 1 (center tap weight is exp(0)=1), safe to rcp.
    float inv = __builtin_amdgcn_rcpf(wsum);
    inv = inv * (2.0f - wsum * inv);   // one Newton step: ~1e-7 rel error
    int oi = y * WW + x;
    outb[oi] = o0 * inv;
    outb[HH * WW + oi] = o1 * inv;
    outb[2 * HH * WW + oi] = o2 * inv;
}

__global__ __launch_bounds__(256) void gauss_psf_kernel(const float* __restrict__ image,
                                                        const float* __restrict__ A,
                                                        float* __restrict__ out) {
    const int x = blockIdx.x * 64 + threadIdx.x;   // blockDim = (64,4)
    const int y = blockIdx.y * 4 + threadIdx.y;
    const int b = blockIdx.z;

    const float* img  = image + (size_t)b * CC * HH * WW;
    const float* Ab   = A + (size_t)b * HH * WW;
    float*       outb = out + (size_t)b * CC * HH * WW;

    // Block-uniform interior test: whole 64x4 block's 11x11 windows in-bounds?
    const int x0 = blockIdx.x * 64, y0 = blockIdx.y * 4;
    const bool interior = (x0 >= RR) && (x0 + 63 < WW - RR) && (y0 >= RR) && (y0 + 3 < HH - RR);

    if (interior) pixel_body<true>(img, Ab, outb, x, y);
    else          pixel_body<false>(img, Ab, outb, x, y);
}

extern "C" void kernel_launch(void* const* d_in, const int* in_sizes, int n_in,
                              void* d_out, int out_size, void* d_ws, size_t ws_size,
                              hipStream_t stream) {
    const float* image = (const float*)d_in[0];
    const float* psf   = (const float*)d_in[1];
    float* out = (float*)d_out;
    float* A   = (float*)d_ws;   // B*H*W floats = 4 MiB scratch

    const int n = BB * HH * WW;
    psf_prep_kernel<<<dim3((n + 255) / 256), dim3(256), 0, stream>>>(psf, A, n);

    dim3 block(64, 4, 1);
    dim3 grid(WW / 64, HH / 4, BB);
    gauss_psf_kernel<<<grid, block, 0, stream>>>(image, A, out);
}